// Round 1
// baseline (28.137 us; speedup 1.0000x reference)
//
#include <hip/hip_runtime.h>
#include <math.h>

#define SEQ 30
#define H 64
#define VOCAB 128000

// K2 geometry: 16 lanes per row, 256 threads/block -> 16 rows per iteration.
#define NB2 1000
#define ITERS2 8              // rows per block = 16 * ITERS2 = 128; 1000*128 = 128000
#define ROWS_PER_BLOCK (16 * ITERS2)

// ws layout (floats):
//  [0..63]       h_new
//  [64]          lse
//  [80..80+NB2)  per-block running max
//  [1200..1200+NB2) per-block running sum(exp)
#define WS_M 80
#define WS_S 1200

// ---------------- K1: attention-sum + GRU step ----------------
__global__ void gru_kernel(const float* __restrict__ input,
                           const float* __restrict__ hidden,
                           const float* __restrict__ W_ih,
                           const float* __restrict__ W_hh,
                           const float* __restrict__ b_ih,
                           const float* __restrict__ b_hh,
                           float* __restrict__ out,
                           float* __restrict__ ws) {
    __shared__ float xs[H], h0s[H], gx[3 * H], gh[3 * H];
    const int t = threadIdx.x;  // 192 threads
    if (t < H) {
        // softmax over singleton axis => attn weights are all 1.0
        float s = 0.f;
#pragma unroll
        for (int i = 0; i < SEQ; ++i) s += input[i * H + t];
        xs[t] = s;
        h0s[t] = hidden[t];
    }
    __syncthreads();
    {
        float a = b_ih[t], b = b_hh[t];
        const float* wi = W_ih + t * H;
        const float* wh = W_hh + t * H;
#pragma unroll
        for (int j = 0; j < H; ++j) {
            a += wi[j] * xs[j];
            b += wh[j] * h0s[j];
        }
        gx[t] = a;
        gh[t] = b;
    }
    __syncthreads();
    if (t < H) {
        const float r = 1.f / (1.f + expf(-(gx[t] + gh[t])));
        const float z = 1.f / (1.f + expf(-(gx[H + t] + gh[H + t])));
        const float n = tanhf(gx[2 * H + t] + r * gh[2 * H + t]);
        const float hn = (1.f - z) * n + z * h0s[t];
        ws[t] = hn;
        out[VOCAB + t] = hn;   // second tuple output: h_new
    }
}

// ---------------- K2: logits = h_new @ W_out^T + b_out, + per-block LSE partials
__global__ void logits_kernel(const float* __restrict__ W_out,
                              const float* __restrict__ b_out,
                              float* __restrict__ out,
                              float* __restrict__ ws) {
    __shared__ float hs[H];
    __shared__ float pm[16], ps[16];
    const int t = threadIdx.x;
    if (t < H) hs[t] = ws[t];
    __syncthreads();

    const int sub = t & 15;
    const float4 hv = ((const float4*)hs)[sub];
    const int base = blockIdx.x * ROWS_PER_BLOCK;
    const float4* __restrict__ W4 = (const float4*)W_out;

    float m = -INFINITY, s = 0.f;
#pragma unroll
    for (int it = 0; it < ITERS2; ++it) {
        const int row = base + it * 16 + (t >> 4);
        // index = base*16 + it*256 + t  -> fully sequential across the block
        const float4 w = W4[row * 16 + sub];
        float d = w.x * hv.x + w.y * hv.y + w.z * hv.z + w.w * hv.w;
#pragma unroll
        for (int off = 1; off < 16; off <<= 1) d += __shfl_xor(d, off);
        const float logit = d + b_out[row];
        if (sub == 0) {
            out[row] = logit;
            // online logsumexp
            if (logit > m) {
                s = s * expf(m - logit) + 1.f;  // expf(-inf)==0 on first iter
                m = logit;
            } else {
                s += expf(logit - m);
            }
        }
    }
    if (sub == 0) { pm[t >> 4] = m; ps[t >> 4] = s; }
    __syncthreads();
    if (t == 0) {
        float M = -INFINITY, S = 0.f;
#pragma unroll
        for (int i = 0; i < 16; ++i) {
            const float m2 = pm[i], s2 = ps[i];
            const float Mn = fmaxf(M, m2);
            S = S * expf(M - Mn) + s2 * expf(m2 - Mn);
            M = Mn;
        }
        ws[WS_M + blockIdx.x] = M;
        ws[WS_S + blockIdx.x] = S;
    }
}

// ---------------- K3: merge per-block partials -> lse ----------------
__global__ void lse_kernel(float* __restrict__ ws) {
    __shared__ float pm[256], ps[256];
    const int t = threadIdx.x;
    float m = -INFINITY, s = 0.f;
    for (int i = t; i < NB2; i += 256) {
        const float m2 = ws[WS_M + i], s2 = ws[WS_S + i];
        const float Mn = fmaxf(m, m2);
        s = s * expf(m - Mn) + s2 * expf(m2 - Mn);
        m = Mn;
    }
    pm[t] = m; ps[t] = s;
    __syncthreads();
    for (int off = 128; off > 0; off >>= 1) {
        if (t < off) {
            const float m2 = pm[t + off], s2 = ps[t + off];
            const float Mn = fmaxf(pm[t], m2);
            ps[t] = ps[t] * expf(pm[t] - Mn) + s2 * expf(m2 - Mn);
            pm[t] = Mn;
        }
        __syncthreads();
    }
    if (t == 0) ws[64] = pm[0] + logf(ps[0]);
}

// ---------------- K4: out[v] = logit[v] - lse (in place, float4) ----------------
__global__ void sub_kernel(float* __restrict__ out, const float* __restrict__ ws) {
    const float lse = ws[64];
    const int i = blockIdx.x * blockDim.x + threadIdx.x;  // 32000 float4s
    float4* o4 = (float4*)out;
    float4 v = o4[i];
    v.x -= lse; v.y -= lse; v.z -= lse; v.w -= lse;
    o4[i] = v;
}

extern "C" void kernel_launch(void* const* d_in, const int* in_sizes, int n_in,
                              void* d_out, int out_size, void* d_ws, size_t ws_size,
                              hipStream_t stream) {
    const float* input  = (const float*)d_in[0];
    const float* hidden = (const float*)d_in[1];
    // d_in[2] = W_attn, d_in[3] = b_attn: dead code (softmax over singleton axis)
    const float* W_ih   = (const float*)d_in[4];
    const float* W_hh   = (const float*)d_in[5];
    const float* b_ih   = (const float*)d_in[6];
    const float* b_hh   = (const float*)d_in[7];
    const float* W_out  = (const float*)d_in[8];
    const float* b_out  = (const float*)d_in[9];
    // d_in[10] = time_step: unused
    float* out = (float*)d_out;
    float* ws  = (float*)d_ws;

    gru_kernel<<<1, 3 * H, 0, stream>>>(input, hidden, W_ih, W_hh, b_ih, b_hh, out, ws);
    logits_kernel<<<NB2, 256, 0, stream>>>(W_out, b_out, out, ws);
    lse_kernel<<<1, 256, 0, stream>>>(ws);
    sub_kernel<<<VOCAB / 4 / 256, 256, 0, stream>>>(out, ws);
}